// Round 11
// baseline (183.376 us; speedup 1.0000x reference)
//
#include <hip/hip_runtime.h>
#include <hip/hip_bf16.h>
#include <math.h>
#include <stdint.h>

#define HC 4
#define DIM 16384                 // hc*hidden
#define MIXN 24
#define NROWS 8192                // B*S
#define RPB 16                    // rows per block (one MFMA M-tile)
#define THREADS 256
#define NWAVE 4
#define KPW (DIM / NWAVE)         // 4096 K per wave
#define NSTEP (KPW / 32)          // 128 MFMA K-steps per wave
#define HC_EPS 1e-5f
#define NORM_EPS 1e-6f

#define PRE_OFF 0
#define POST_OFF (NROWS * HC)
#define COMB_OFF (2 * NROWS * HC)

typedef float f32x4 __attribute__((ext_vector_type(4)));
typedef float accf4 __attribute__((ext_vector_type(4)));
typedef short bf16x8 __attribute__((ext_vector_type(8)));

__device__ __forceinline__ short f2bf(float x) {
    union { __hip_bfloat16 h; short s; } u;
    u.h = __float2bfloat16(x);
    return u.s;
}

__global__ __launch_bounds__(THREADS) void hyperconn_mfma(
    const float* __restrict__ hs,    // [NROWS][DIM]
    const float* __restrict__ fn,    // [MIXN][DIM]
    const float* __restrict__ base,  // [MIXN]
    const float* __restrict__ scale, // [3]
    float* __restrict__ out)
{
    const int tid  = threadIdx.x;
    const int wave = tid >> 6;
    const int lane = tid & 63;
    const int l15  = lane & 15;
    const int kg   = lane >> 4;          // k-group 0..3
    const int row0 = blockIdx.x * RPB;

    __shared__ float sC[NWAVE][RPB][MIXN];   // per-wave partial mix
    __shared__ float sS[NWAVE][RPB];         // per-wave partial ssq
    __shared__ float sMix[RPB][25];          // final mix + ssq

    // A fragment source: row = l15, 8 consecutive k at kg*8 (128B/row coalesced).
    // B tiles: tile0 = fn cols 0-15, tile1 = fn cols 8-23 (overlap -> no pad).
    const float* ap  = hs + (size_t)(row0 + l15) * DIM + wave * KPW + kg * 8;
    const float* bp0 = fn + (size_t)l15 * DIM       + wave * KPW + kg * 8;
    const float* bp1 = fn + (size_t)(8 + l15) * DIM + wave * KPW + kg * 8;

    accf4 acc0 = {0.f, 0.f, 0.f, 0.f};
    accf4 acc1 = {0.f, 0.f, 0.f, 0.f};
    float ssq = 0.f;

    // depth-2 register prefetch, hand-unrolled x2 (static names; rule #20)
    f32x4 a0A, a1A, c0A, c1A, d0A, d1A;
    f32x4 a0B, a1B, c0B, c1B, d0B, d1B;

#define LOADSET(S, T) do { \
    const float* _a = ap  + (size_t)(T) * 32; \
    const float* _c = bp0 + (size_t)(T) * 32; \
    const float* _d = bp1 + (size_t)(T) * 32; \
    a0##S = *(const f32x4*)_a;  a1##S = *(const f32x4*)(_a + 4); \
    c0##S = *(const f32x4*)_c;  c1##S = *(const f32x4*)(_c + 4); \
    d0##S = *(const f32x4*)_d;  d1##S = *(const f32x4*)(_d + 4); \
} while (0)

#define COMPSET(S) do { \
    ssq = fmaf(a0##S.x, a0##S.x, ssq); ssq = fmaf(a0##S.y, a0##S.y, ssq); \
    ssq = fmaf(a0##S.z, a0##S.z, ssq); ssq = fmaf(a0##S.w, a0##S.w, ssq); \
    ssq = fmaf(a1##S.x, a1##S.x, ssq); ssq = fmaf(a1##S.y, a1##S.y, ssq); \
    ssq = fmaf(a1##S.z, a1##S.z, ssq); ssq = fmaf(a1##S.w, a1##S.w, ssq); \
    bf16x8 af  = { f2bf(a0##S.x), f2bf(a0##S.y), f2bf(a0##S.z), f2bf(a0##S.w), \
                   f2bf(a1##S.x), f2bf(a1##S.y), f2bf(a1##S.z), f2bf(a1##S.w) }; \
    bf16x8 bf0 = { f2bf(c0##S.x), f2bf(c0##S.y), f2bf(c0##S.z), f2bf(c0##S.w), \
                   f2bf(c1##S.x), f2bf(c1##S.y), f2bf(c1##S.z), f2bf(c1##S.w) }; \
    bf16x8 bf1 = { f2bf(d0##S.x), f2bf(d0##S.y), f2bf(d0##S.z), f2bf(d0##S.w), \
                   f2bf(d1##S.x), f2bf(d1##S.y), f2bf(d1##S.z), f2bf(d1##S.w) }; \
    acc0 = __builtin_amdgcn_mfma_f32_16x16x32_bf16(af, bf0, acc0, 0, 0, 0); \
    acc1 = __builtin_amdgcn_mfma_f32_16x16x32_bf16(af, bf1, acc1, 0, 0, 0); \
} while (0)

    LOADSET(A, 0);
    #pragma unroll 1
    for (int t = 0; t < NSTEP; t += 2) {
        LOADSET(B, t + 1);                 // NSTEP even -> t+1 always valid
        COMPSET(A);
        if (t + 2 < NSTEP) LOADSET(A, t + 2);
        COMPSET(B);
    }
#undef LOADSET
#undef COMPSET

    // ssq: sum the 4 k-groups (lanes sharing l15) -> full row ssq for this wave's K
    ssq += __shfl_xor(ssq, 16, 64);
    ssq += __shfl_xor(ssq, 32, 64);
    if (lane < 16) sS[wave][lane] = ssq;

    // C layout (HW-verified): col = lane&15, row = (lane>>4)*4 + reg
    {
        const int orow = kg * 4;
        #pragma unroll
        for (int i = 0; i < 4; ++i)
            sC[wave][orow + i][l15] = acc0[i];          // cols 0-15
        if (l15 >= 8) {
            #pragma unroll
            for (int i = 0; i < 4; ++i)
                sC[wave][orow + i][l15 + 8] = acc1[i];  // cols 16-23 (tile cols 8-23)
        }
    }
    __syncthreads();

    // cross-wave reduction: mix[16][24] + ssq
    for (int idx = tid; idx < RPB * MIXN; idx += THREADS) {
        const int r = idx / MIXN, c = idx % MIXN;
        sMix[r][c] = sC[0][r][c] + sC[1][r][c] + sC[2][r][c] + sC[3][r][c];
    }
    if (tid < RPB)
        sMix[tid][24] = sS[0][tid] + sS[1][tid] + sS[2][tid] + sS[3][tid];
    __syncthreads();

    // epilogue: one thread per row
    if (tid < RPB) {
        const int row = row0 + tid;
        const float* v = &sMix[tid][0];
        const float rs = 1.0f / sqrtf(v[24] * (1.0f / (float)DIM) + NORM_EPS);
        const float s0 = scale[0], s1 = scale[1], s2 = scale[2];

        #pragma unroll
        for (int i = 0; i < HC; ++i) {
            const float z = v[i] * rs * s0 + base[i];
            out[PRE_OFF + row * HC + i] = 1.0f / (1.0f + expf(-z)) + HC_EPS;
        }
        #pragma unroll
        for (int i = 0; i < HC; ++i) {
            const float z = v[HC + i] * rs * s1 + base[HC + i];
            out[POST_OFF + row * HC + i] = 2.0f / (1.0f + expf(-z));
        }

        float c[HC][HC];
        #pragma unroll
        for (int i = 0; i < HC; ++i) {
            float l[HC];
            #pragma unroll
            for (int j = 0; j < HC; ++j)
                l[j] = v[2 * HC + i * HC + j] * rs * s2 + base[2 * HC + i * HC + j];
            const float mx = fmaxf(fmaxf(l[0], l[1]), fmaxf(l[2], l[3]));
            float e[HC];
            float sum = 0.0f;
            #pragma unroll
            for (int j = 0; j < HC; ++j) { e[j] = expf(l[j] - mx); sum += e[j]; }
            const float inv = 1.0f / sum;
            #pragma unroll
            for (int j = 0; j < HC; ++j) c[i][j] = e[j] * inv + HC_EPS;
        }
        #pragma unroll
        for (int j = 0; j < HC; ++j) {
            const float cs = c[0][j] + c[1][j] + c[2][j] + c[3][j] + HC_EPS;
            const float inv = 1.0f / cs;
            c[0][j] *= inv; c[1][j] *= inv; c[2][j] *= inv; c[3][j] *= inv;
        }
        #pragma unroll
        for (int it = 0; it < 4; ++it) {
            #pragma unroll
            for (int i = 0; i < HC; ++i) {
                const float rsum = c[i][0] + c[i][1] + c[i][2] + c[i][3] + HC_EPS;
                const float inv = 1.0f / rsum;
                c[i][0] *= inv; c[i][1] *= inv; c[i][2] *= inv; c[i][3] *= inv;
            }
            #pragma unroll
            for (int j = 0; j < HC; ++j) {
                const float cs = c[0][j] + c[1][j] + c[2][j] + c[3][j] + HC_EPS;
                const float inv = 1.0f / cs;
                c[0][j] *= inv; c[1][j] *= inv; c[2][j] *= inv; c[3][j] *= inv;
            }
        }
        #pragma unroll
        for (int i = 0; i < HC; ++i)
            #pragma unroll
            for (int j = 0; j < HC; ++j)
                out[COMB_OFF + row * (HC * HC) + i * HC + j] = c[i][j];
    }
}

extern "C" void kernel_launch(void* const* d_in, const int* in_sizes, int n_in,
                              void* d_out, int out_size, void* d_ws, size_t ws_size,
                              hipStream_t stream) {
    const float* hs    = (const float*)d_in[0];
    const float* fn    = (const float*)d_in[1];
    const float* base  = (const float*)d_in[2];
    const float* scale = (const float*)d_in[3];
    float* out = (float*)d_out;

    const int grid = NROWS / RPB;  // 512 blocks (2/CU, co-resident)
    hyperconn_mfma<<<grid, THREADS, 0, stream>>>(hs, fn, base, scale, out);
}

// Round 12
// 147.234 us; speedup vs baseline: 1.2455x; 1.2455x over previous
//
#include <hip/hip_runtime.h>
#include <hip/hip_bf16.h>
#include <math.h>
#include <stdint.h>

#define HC 4
#define DIM 16384                  // hc*hidden
#define MIXN 24
#define NROWS 8192                 // B*S
#define KSPLIT 16                  // k-slices
#define KSL (DIM / KSPLIT)         // 1024 k per slice
#define NSTEPS (KSL / 32)          // 32 MFMA k-steps per slice
#define NSTREAM 32                 // row streams
#define ROWS_PER_STREAM (NROWS / NSTREAM)   // 256
#define THREADS1 512
#define NWAVE 8
#define ROWS_PER_BITER (NWAVE * 16)         // 128 rows per block-iteration
#define NITER (ROWS_PER_STREAM / ROWS_PER_BITER)  // 2
#define HC_EPS 1e-5f
#define NORM_EPS 1e-6f

#define PRE_OFF 0
#define POST_OFF (NROWS * HC)
#define COMB_OFF (2 * NROWS * HC)

typedef float f32x4 __attribute__((ext_vector_type(4)));
typedef float accf4 __attribute__((ext_vector_type(4)));
typedef short bf16x8 __attribute__((ext_vector_type(8)));

__device__ __forceinline__ short f2bf(float x) {
    union { __hip_bfloat16 h; short s; } u;
    u.h = __float2bfloat16(x);
    return u.s;
}

// ---------------- kernel 1: split-K partial GEMM + ssq ----------------
// B (fn) lives in LDS as pre-swizzled bf16 MFMA B-fragments -> zero global
// fn traffic in the main loop. Waves run barrier-free, each streaming its
// own 16-row A-tiles from HBM with depth-4 register prefetch.
__global__ __launch_bounds__(THREADS1) void hyper_k1(
    const float* __restrict__ hs,   // [NROWS][DIM]
    const float* __restrict__ fn,   // [MIXN][DIM]
    float* __restrict__ ws)         // [512*16][16][25] partials
{
    const int tid  = threadIdx.x;
    const int wave = tid >> 6;
    const int lane = tid & 63;
    const int l15  = lane & 15;
    const int kg   = lane >> 4;
    const int ks     = blockIdx.x & (KSPLIT - 1);
    const int stream = blockIdx.x >> 4;

    // [tile 0|1][step][lane*8 bf16] ; tile0 = fn cols 0-15, tile1 = cols 8-23
    __shared__ __align__(16) short s_fn[2][NSTEPS][64 * 8];   // 64 KB

    // ---- one-time fill: fp32 fn slice -> bf16 B-fragment layout ----
    // mapping derived from R11's validated direct loads:
    //   tile0 lane l step s reads fn[col=l&15      ][32s + (l>>4)*8 + e]
    //   tile1 lane l step s reads fn[col=8 + (l&15)][32s + (l>>4)*8 + e]
    #pragma unroll 1
    for (int p = 0; p < (MIXN * KSL / 4) / THREADS1; ++p) {   // 12 passes
        const int q4 = (p * THREADS1 + tid) * 4;   // float idx within slice
        const int c  = q4 >> 10;                    // fn col 0..23
        const int kk = q4 & 1023;                   // k within slice
        const f32x4 v = *(const f32x4*)(fn + (size_t)c * DIM + ks * KSL + kk);
        #pragma unroll
        for (int e4 = 0; e4 < 4; ++e4) {
            const int k2 = kk + e4;
            const int s = k2 >> 5, w = k2 & 31, g = w >> 3, e = w & 7;
            const short bv = f2bf(v[e4]);
            if (c < 16) s_fn[0][s][(g * 16 + c) * 8 + e] = bv;
            if (c >= 8) s_fn[1][s][(g * 16 + (c - 8)) * 8 + e] = bv;
        }
    }
    __syncthreads();

    #pragma unroll 1
    for (int it = 0; it < NITER; ++it) {
        const int rowbase = stream * ROWS_PER_STREAM + it * ROWS_PER_BITER + wave * 16;
        const float* abase = hs + (size_t)(rowbase + l15) * DIM + ks * KSL + kg * 8;

        accf4 acc0 = {0.f, 0.f, 0.f, 0.f};
        accf4 acc1 = {0.f, 0.f, 0.f, 0.f};
        float ssq = 0.f;

        f32x4 A0, A1, B0, B1, C0, C1, D0, D1;   // depth-4 prefetch ring

#define ALD(Pa, Pb, S) do { \
    const float* _a = abase + (size_t)(S) * 32; \
    Pa = *(const f32x4*)_a; Pb = *(const f32x4*)(_a + 4); \
} while (0)

#define ACP(Pa, Pb, S) do { \
    ssq = fmaf(Pa.x, Pa.x, ssq); ssq = fmaf(Pa.y, Pa.y, ssq); \
    ssq = fmaf(Pa.z, Pa.z, ssq); ssq = fmaf(Pa.w, Pa.w, ssq); \
    ssq = fmaf(Pb.x, Pb.x, ssq); ssq = fmaf(Pb.y, Pb.y, ssq); \
    ssq = fmaf(Pb.z, Pb.z, ssq); ssq = fmaf(Pb.w, Pb.w, ssq); \
    bf16x8 af = { f2bf(Pa.x), f2bf(Pa.y), f2bf(Pa.z), f2bf(Pa.w), \
                  f2bf(Pb.x), f2bf(Pb.y), f2bf(Pb.z), f2bf(Pb.w) }; \
    const bf16x8 b0 = *(const bf16x8*)&s_fn[0][S][lane * 8]; \
    const bf16x8 b1 = *(const bf16x8*)&s_fn[1][S][lane * 8]; \
    acc0 = __builtin_amdgcn_mfma_f32_16x16x32_bf16(af, b0, acc0, 0, 0, 0); \
    acc1 = __builtin_amdgcn_mfma_f32_16x16x32_bf16(af, b1, acc1, 0, 0, 0); \
} while (0)

        ALD(A0, A1, 0); ALD(B0, B1, 1); ALD(C0, C1, 2); ALD(D0, D1, 3);
        #pragma unroll 1
        for (int s = 0; s < NSTEPS; s += 4) {
            ACP(A0, A1, s);     if (s + 4 < NSTEPS) ALD(A0, A1, s + 4);
            ACP(B0, B1, s + 1); if (s + 5 < NSTEPS) ALD(B0, B1, s + 5);
            ACP(C0, C1, s + 2); if (s + 6 < NSTEPS) ALD(C0, C1, s + 6);
            ACP(D0, D1, s + 3); if (s + 7 < NSTEPS) ALD(D0, D1, s + 7);
        }
#undef ALD
#undef ACP

        // row-ssq: sum the 4 k-groups (lanes l15, l15+16, l15+32, l15+48)
        ssq += __shfl_xor(ssq, 16, 64);
        ssq += __shfl_xor(ssq, 32, 64);

        // partial writeout; C layout validated in R11: col=lane&15, row=kg*4+i
        const int rt = rowbase >> 4;                       // global rowtile 0..511
        float* w = ws + (size_t)(rt * KSPLIT + ks) * (16 * 25);
        #pragma unroll
        for (int i = 0; i < 4; ++i)
            w[(kg * 4 + i) * 25 + l15] = acc0[i];          // cols 0-15
        if (l15 >= 8) {
            #pragma unroll
            for (int i = 0; i < 4; ++i)
                w[(kg * 4 + i) * 25 + l15 + 8] = acc1[i];  // cols 16-23
        }
        if (lane < 16) w[lane * 25 + 24] = ssq;
    }
}

// ---------------- kernel 2: reduce k-slices + epilogue ----------------
__global__ __launch_bounds__(256) void hyper_k2(
    const float* __restrict__ ws,
    const float* __restrict__ base,
    const float* __restrict__ scale,
    float* __restrict__ out)
{
    const int r  = blockIdx.x * 256 + threadIdx.x;   // row 0..8191
    const int rt = r >> 4, rr = r & 15;

    float v[25];
    #pragma unroll
    for (int c = 0; c < 25; ++c) v[c] = 0.f;
    #pragma unroll 1
    for (int ks = 0; ks < KSPLIT; ++ks) {
        const float* w = ws + (size_t)(rt * KSPLIT + ks) * (16 * 25) + rr * 25;
        #pragma unroll
        for (int c = 0; c < 25; ++c) v[c] += w[c];
    }

    const float rs = 1.0f / sqrtf(v[24] * (1.0f / (float)DIM) + NORM_EPS);
    const float s0 = scale[0], s1 = scale[1], s2 = scale[2];

    #pragma unroll
    for (int i = 0; i < HC; ++i) {
        const float z = v[i] * rs * s0 + base[i];
        out[PRE_OFF + r * HC + i] = 1.0f / (1.0f + expf(-z)) + HC_EPS;
    }
    #pragma unroll
    for (int i = 0; i < HC; ++i) {
        const float z = v[HC + i] * rs * s1 + base[HC + i];
        out[POST_OFF + r * HC + i] = 2.0f / (1.0f + expf(-z));
    }

    float c[HC][HC];
    #pragma unroll
    for (int i = 0; i < HC; ++i) {
        float l[HC];
        #pragma unroll
        for (int j = 0; j < HC; ++j)
            l[j] = v[2 * HC + i * HC + j] * rs * s2 + base[2 * HC + i * HC + j];
        const float mx = fmaxf(fmaxf(l[0], l[1]), fmaxf(l[2], l[3]));
        float e[HC];
        float sum = 0.0f;
        #pragma unroll
        for (int j = 0; j < HC; ++j) { e[j] = expf(l[j] - mx); sum += e[j]; }
        const float inv = 1.0f / sum;
        #pragma unroll
        for (int j = 0; j < HC; ++j) c[i][j] = e[j] * inv + HC_EPS;
    }
    #pragma unroll
    for (int j = 0; j < HC; ++j) {
        const float cs = c[0][j] + c[1][j] + c[2][j] + c[3][j] + HC_EPS;
        const float inv = 1.0f / cs;
        c[0][j] *= inv; c[1][j] *= inv; c[2][j] *= inv; c[3][j] *= inv;
    }
    #pragma unroll
    for (int it = 0; it < 4; ++it) {
        #pragma unroll
        for (int i = 0; i < HC; ++i) {
            const float rsum = c[i][0] + c[i][1] + c[i][2] + c[i][3] + HC_EPS;
            const float inv = 1.0f / rsum;
            c[i][0] *= inv; c[i][1] *= inv; c[i][2] *= inv; c[i][3] *= inv;
        }
        #pragma unroll
        for (int j = 0; j < HC; ++j) {
            const float cs = c[0][j] + c[1][j] + c[2][j] + c[3][j] + HC_EPS;
            const float inv = 1.0f / cs;
            c[0][j] *= inv; c[1][j] *= inv; c[2][j] *= inv; c[3][j] *= inv;
        }
    }
    #pragma unroll
    for (int i = 0; i < HC; ++i)
        #pragma unroll
        for (int j = 0; j < HC; ++j)
            out[COMB_OFF + r * (HC * HC) + i * HC + j] = c[i][j];
}

extern "C" void kernel_launch(void* const* d_in, const int* in_sizes, int n_in,
                              void* d_out, int out_size, void* d_ws, size_t ws_size,
                              hipStream_t stream) {
    const float* hs    = (const float*)d_in[0];
    const float* fn    = (const float*)d_in[1];
    const float* base  = (const float*)d_in[2];
    const float* scale = (const float*)d_in[3];
    float* out = (float*)d_out;
    float* ws  = (float*)d_ws;   // 512*16*16*25*4 B = 13.1 MB

    hyper_k1<<<KSPLIT * NSTREAM, THREADS1, 0, stream>>>(hs, fn, ws);
    hyper_k2<<<NROWS / 256, 256, 0, stream>>>(ws, base, scale, out);
}